// Round 1
// baseline (150.021 us; speedup 1.0000x reference)
//
#include <hip/hip_runtime.h>

#define B_SZ 16
#define N_BOX 96
#define EPSF 1e-7f

// ---- static geometry -------------------------------------------------------
// level l: hl = wl = 1024 >> l, plane = wl*wl
// plane sizes: 1048576, 262144, 65536, 16384, 4096
// bit offsets (bits) = 16 * cumulative plane sizes:
//   l0: 0
//   l1: 16777216
//   l2: 20971520
//   l3: 22020096
//   l4: 22282240
// total bits = 22347776 -> 698368 words -> 2793472 bytes
#define MASK_BYTES 2793472u
#define ACC_COUNT  (B_SZ * 5)

__device__ __forceinline__ unsigned level_bit_off(int l) {
    switch (l) {
        case 0:  return 0u;
        case 1:  return 16777216u;
        case 2:  return 20971520u;
        case 3:  return 22020096u;
        default: return 22282240u;
    }
}

// ---- kernel 1: rasterize selected boxes into the bit mask ------------------
__global__ __launch_bounds__(64)
void raster_kernel(const float* __restrict__ bboxs,
                   const int* __restrict__ hp, const int* __restrict__ wp,
                   unsigned* __restrict__ maskbits)
{
    int gid = blockIdx.x;                 // [0, B*5*N)
    int n = gid % N_BOX;
    int l = (gid / N_BOX) % 5;
    int b = gid / (N_BOX * 5);

    const float* bx = bboxs + (b * N_BOX + n) * 5;
    float x1 = bx[0], y1 = bx[1], x2 = bx[2], y2 = bx[3], lb = bx[4];
    float Wf = (float)(*wp), Hf = (float)(*hp);

    bool valid = (lb != -1.0f) && (x1 <= Wf) && (y1 <= Hf) && (x2 <= Wf) && (y2 <= Hf);
    if (!valid) return;

    float area = (x2 - x1) * (y2 - y1);
    double based = (double)(32 << l);
    float mn  = (float)(based * based * 0.5);
    float mxv = (float)((based * 1.58) * (based * 1.58) * 2.0);
    if (!(area >= mn && area <= mxv)) return;

    int wl = 1024 >> l;                   // hl == wl
    float sx = (float)wl / Wf;
    float sy = (float)wl / Hf;

    int ix1 = (int)fmaxf(floorf(x1 * sx), 0.0f);
    int iy1 = (int)fmaxf(floorf(y1 * sy), 0.0f);
    int ix2 = (int)fminf(ceilf(x2 * sx) + 1.0f, (float)wl);
    int iy2 = (int)fminf(ceilf(y2 * sy) + 1.0f, (float)wl);
    if (ix2 <= ix1 || iy2 <= iy1) return;

    unsigned bitOff = level_bit_off(l) + (unsigned)b * (unsigned)(wl * wl);
    int nrows = iy2 - iy1;
    for (int rr = (int)threadIdx.x; rr < nrows; rr += 64) {
        int r = iy1 + rr;
        unsigned rs = bitOff + (unsigned)r * (unsigned)wl + (unsigned)ix1;
        unsigned re = rs + (unsigned)(ix2 - ix1);          // exclusive
        unsigned w0 = rs >> 5, w1 = (re - 1u) >> 5;
        for (unsigned w = w0; w <= w1; ++w) {
            unsigned lo = (w == w0) ? (rs & 31u) : 0u;
            unsigned hi = (w == w1) ? (((re - 1u) & 31u) + 1u) : 32u;
            unsigned m = (hi == 32u ? 0xffffffffu : ((1u << hi) - 1u)) & ~((1u << lo) - 1u);
            atomicOr(&maskbits[w], m);
        }
    }
}

// ---- kernel 2: streaming BCE reduction --------------------------------------
// blocks per level = 16*plane/1024 : 16384, 4096, 1024, 256, 64 (total 21824)
__global__ __launch_bounds__(256)
void bce_kernel(const float* __restrict__ a0, const float* __restrict__ a1,
                const float* __restrict__ a2, const float* __restrict__ a3,
                const float* __restrict__ a4,
                const unsigned* __restrict__ maskbits,
                float* __restrict__ acc)
{
    int bid = blockIdx.x;
    int l, start;
    const float* att;
    if (bid < 16384)      { l = 0; start = 0;     att = a0; }
    else if (bid < 20480) { l = 1; start = 16384; att = a1; }
    else if (bid < 21504) { l = 2; start = 20480; att = a2; }
    else if (bid < 21760) { l = 3; start = 21504; att = a3; }
    else                  { l = 4; start = 21760; att = a4; }

    int logPlane = 20 - 2 * l;
    unsigned gp = (unsigned)(bid - start) * 1024u + threadIdx.x * 4u;
    int b = (int)(gp >> logPlane);        // block never straddles a plane

    float4 av = reinterpret_cast<const float4*>(att)[gp >> 2];
    unsigned bidx = level_bit_off(l) + gp;
    unsigned wrd = maskbits[bidx >> 5];
    unsigned nib = (wrd >> (bidx & 31u)) & 0xFu;

    float pv[4] = {av.x, av.y, av.z, av.w};
    float s = 0.0f;
    #pragma unroll
    for (int j = 0; j < 4; ++j) {
        float p = fminf(fmaxf(pv[j], EPSF), 1.0f - EPSF);
        float q = ((nib >> j) & 1u) ? p : (1.0f - p);
        s -= __logf(q);
    }

    // wave reduce (64-wide) then LDS across 4 waves
    #pragma unroll
    for (int off = 32; off > 0; off >>= 1)
        s += __shfl_down(s, off, 64);
    __shared__ float wsum[4];
    int lane = threadIdx.x & 63, wv = threadIdx.x >> 6;
    if (lane == 0) wsum[wv] = s;
    __syncthreads();
    if (threadIdx.x == 0) {
        float t = wsum[0] + wsum[1] + wsum[2] + wsum[3];
        atomicAdd(&acc[b * 5 + l], t);
    }
}

// ---- kernel 3: finalize ------------------------------------------------------
__global__ __launch_bounds__(256)
void finalize_kernel(const float* __restrict__ bboxs,
                     const int* __restrict__ hp, const int* __restrict__ wp,
                     const float* __restrict__ acc, float* __restrict__ out)
{
    __shared__ int hasbox[B_SZ];
    if (threadIdx.x < B_SZ) hasbox[threadIdx.x] = 0;
    __syncthreads();
    float Wf = (float)(*wp), Hf = (float)(*hp);
    for (int i = (int)threadIdx.x; i < B_SZ * N_BOX; i += 256) {
        const float* bx = bboxs + i * 5;
        if (bx[4] != -1.0f && bx[0] <= Wf && bx[1] <= Hf && bx[2] <= Wf && bx[3] <= Hf)
            hasbox[i / N_BOX] = 1;        // benign race, same value
    }
    __syncthreads();
    if (threadIdx.x == 0) {
        double tot = 0.0;
        for (int b = 0; b < B_SZ; ++b) {
            if (!hasbox[b]) continue;
            double s = 0.0;
            for (int l = 0; l < 5; ++l) {
                int wl = 1024 >> l;
                s += (double)acc[b * 5 + l] / (double)(wl * wl);
            }
            tot += s / 5.0;
        }
        out[0] = (float)(tot / (double)B_SZ);
    }
}

// ---- launch ------------------------------------------------------------------
extern "C" void kernel_launch(void* const* d_in, const int* in_sizes, int n_in,
                              void* d_out, int out_size, void* d_ws, size_t ws_size,
                              hipStream_t stream)
{
    const float* a0 = (const float*)d_in[0];
    const float* a1 = (const float*)d_in[1];
    const float* a2 = (const float*)d_in[2];
    const float* a3 = (const float*)d_in[3];
    const float* a4 = (const float*)d_in[4];
    const float* bboxs = (const float*)d_in[5];
    const int* hp = (const int*)d_in[6];
    const int* wp = (const int*)d_in[7];

    unsigned* maskbits = (unsigned*)d_ws;
    float* acc = (float*)((char*)d_ws + MASK_BYTES);

    hipMemsetAsync(d_ws, 0, MASK_BYTES + ACC_COUNT * sizeof(float), stream);
    raster_kernel<<<B_SZ * 5 * N_BOX, 64, 0, stream>>>(bboxs, hp, wp, maskbits);
    bce_kernel<<<21824, 256, 0, stream>>>(a0, a1, a2, a3, a4, maskbits, acc);
    finalize_kernel<<<1, 256, 0, stream>>>(bboxs, hp, wp, acc, (float*)d_out);
}

// Round 2
// 41.558 us; speedup vs baseline: 3.6099x; 3.6099x over previous
//
#include <hip/hip_runtime.h>

#define B_SZ 16
#define N_BOX 96
#define EPSF 1e-7f

// ---- static geometry -------------------------------------------------------
// level l: hl = wl = 1024 >> l, plane_px = wl*wl
// plane px: 1048576, 262144, 65536, 16384, 4096
// bit offsets (bits) = 16 * cumulative plane sizes
// total bits = 22347776 -> 698368 words -> 2793472 bytes
#define MASK_BYTES 2793472u
#define ACC_STRIDE 32            // floats; 128 B per (b,l) slot -> own cacheline
#define ACC_BYTES  (B_SZ * 5 * ACC_STRIDE * 4)

__device__ __forceinline__ unsigned level_bit_off(int l) {
    switch (l) {
        case 0:  return 0u;
        case 1:  return 16777216u;
        case 2:  return 20971520u;
        case 3:  return 22020096u;
        default: return 22282240u;
    }
}

// ---- kernel 1: rasterize selected boxes into the bit mask ------------------
__global__ __launch_bounds__(64)
void raster_kernel(const float* __restrict__ bboxs,
                   const int* __restrict__ hp, const int* __restrict__ wp,
                   unsigned* __restrict__ maskbits)
{
    int gid = blockIdx.x;                 // [0, B*5*N)
    int n = gid % N_BOX;
    int l = (gid / N_BOX) % 5;
    int b = gid / (N_BOX * 5);

    const float* bx = bboxs + (b * N_BOX + n) * 5;
    float x1 = bx[0], y1 = bx[1], x2 = bx[2], y2 = bx[3], lb = bx[4];
    float Wf = (float)(*wp), Hf = (float)(*hp);

    bool valid = (lb != -1.0f) && (x1 <= Wf) && (y1 <= Hf) && (x2 <= Wf) && (y2 <= Hf);
    if (!valid) return;

    float area = (x2 - x1) * (y2 - y1);
    double based = (double)(32 << l);
    float mn  = (float)(based * based * 0.5);
    float mxv = (float)((based * 1.58) * (based * 1.58) * 2.0);
    if (!(area >= mn && area <= mxv)) return;

    int wl = 1024 >> l;                   // hl == wl
    float sx = (float)wl / Wf;
    float sy = (float)wl / Hf;

    int ix1 = (int)fmaxf(floorf(x1 * sx), 0.0f);
    int iy1 = (int)fmaxf(floorf(y1 * sy), 0.0f);
    int ix2 = (int)fminf(ceilf(x2 * sx) + 1.0f, (float)wl);
    int iy2 = (int)fminf(ceilf(y2 * sy) + 1.0f, (float)wl);
    if (ix2 <= ix1 || iy2 <= iy1) return;

    unsigned bitOff = level_bit_off(l) + (unsigned)b * (unsigned)(wl * wl);
    int nrows = iy2 - iy1;
    for (int rr = (int)threadIdx.x; rr < nrows; rr += 64) {
        int r = iy1 + rr;
        unsigned rs = bitOff + (unsigned)r * (unsigned)wl + (unsigned)ix1;
        unsigned re = rs + (unsigned)(ix2 - ix1);          // exclusive
        unsigned w0 = rs >> 5, w1 = (re - 1u) >> 5;
        for (unsigned w = w0; w <= w1; ++w) {
            unsigned lo = (w == w0) ? (rs & 31u) : 0u;
            unsigned hi = (w == w1) ? (((re - 1u) & 31u) + 1u) : 32u;
            unsigned m = (hi == 32u ? 0xffffffffu : ((1u << hi) - 1u)) & ~((1u << lo) - 1u);
            atomicOr(&maskbits[w], m);
        }
    }
}

// ---- kernel 2: streaming BCE reduction --------------------------------------
// blocks per plane: l0:64 l1:16 l2:4 l3:1 l4:1 ; level block starts:
//   l0: 0..1023, l1: 1024..1279, l2: 1280..1343, l3: 1344..1359, l4: 1360..1375
// per-block f4 count: 4096 (l0..l3), 1024 (l4); 16 (or 4) f4 per thread.
__global__ __launch_bounds__(256)
void bce_kernel(const float* __restrict__ a0, const float* __restrict__ a1,
                const float* __restrict__ a2, const float* __restrict__ a3,
                const float* __restrict__ a4,
                const unsigned* __restrict__ maskbits,
                float* __restrict__ acc)
{
    int bid = blockIdx.x;
    int l, start, bppShift;               // blocksPerPlane = 1<<bppShift
    const float* att;
    if (bid < 1024)      { l = 0; start = 0;    bppShift = 6; att = a0; }
    else if (bid < 1280) { l = 1; start = 1024; bppShift = 4; att = a1; }
    else if (bid < 1344) { l = 2; start = 1280; bppShift = 2; att = a2; }
    else if (bid < 1360) { l = 3; start = 1344; bppShift = 0; att = a3; }
    else                 { l = 4; start = 1360; bppShift = 0; att = a4; }

    int planeF4 = 1 << (18 - 2 * l);      // plane_px / 4
    int bil = bid - start;
    int b     = bil >> bppShift;
    int chunk = bil & ((1 << bppShift) - 1);
    int nf4   = planeF4 >> bppShift;      // 4096, or 1024 at l4
    unsigned gf4base = (unsigned)b * (unsigned)planeF4 + (unsigned)(chunk * nf4);
    unsigned lvlBit  = level_bit_off(l);

    float s = 0.0f;
    for (int j0 = 0; j0 < nf4; j0 += 1024) {
        float4 av[4];
        unsigned nib[4];
        #pragma unroll
        for (int u = 0; u < 4; ++u) {
            unsigned gf4 = gf4base + (unsigned)(j0 + u * 256) + threadIdx.x;
            av[u] = reinterpret_cast<const float4*>(att)[gf4];
            unsigned bidx = lvlBit + gf4 * 4u;
            nib[u] = (maskbits[bidx >> 5] >> (bidx & 31u)) & 0xFu;
        }
        #pragma unroll
        for (int u = 0; u < 4; ++u) {
            float pv[4] = {av[u].x, av[u].y, av[u].z, av[u].w};
            #pragma unroll
            for (int j = 0; j < 4; ++j) {
                float p = fminf(fmaxf(pv[j], EPSF), 1.0f - EPSF);
                float q = ((nib[u] >> j) & 1u) ? p : (1.0f - p);
                s -= __logf(q);
            }
        }
    }

    // wave reduce (64-wide) then LDS across 4 waves
    #pragma unroll
    for (int off = 32; off > 0; off >>= 1)
        s += __shfl_down(s, off, 64);
    __shared__ float wsum[4];
    int lane = threadIdx.x & 63, wv = threadIdx.x >> 6;
    if (lane == 0) wsum[wv] = s;
    __syncthreads();
    if (threadIdx.x == 0) {
        float t = wsum[0] + wsum[1] + wsum[2] + wsum[3];
        atomicAdd(&acc[(b * 5 + l) * ACC_STRIDE], t);
    }
}

// ---- kernel 3: finalize ------------------------------------------------------
__global__ __launch_bounds__(256)
void finalize_kernel(const float* __restrict__ bboxs,
                     const int* __restrict__ hp, const int* __restrict__ wp,
                     const float* __restrict__ acc, float* __restrict__ out)
{
    __shared__ int hasbox[B_SZ];
    if (threadIdx.x < B_SZ) hasbox[threadIdx.x] = 0;
    __syncthreads();
    float Wf = (float)(*wp), Hf = (float)(*hp);
    for (int i = (int)threadIdx.x; i < B_SZ * N_BOX; i += 256) {
        const float* bx = bboxs + i * 5;
        if (bx[4] != -1.0f && bx[0] <= Wf && bx[1] <= Hf && bx[2] <= Wf && bx[3] <= Hf)
            hasbox[i / N_BOX] = 1;        // benign race, same value
    }
    __syncthreads();
    if (threadIdx.x == 0) {
        double tot = 0.0;
        for (int b = 0; b < B_SZ; ++b) {
            if (!hasbox[b]) continue;
            double s = 0.0;
            for (int l = 0; l < 5; ++l) {
                int wl = 1024 >> l;
                s += (double)acc[(b * 5 + l) * ACC_STRIDE] / (double)(wl * wl);
            }
            tot += s / 5.0;
        }
        out[0] = (float)(tot / (double)B_SZ);
    }
}

// ---- launch ------------------------------------------------------------------
extern "C" void kernel_launch(void* const* d_in, const int* in_sizes, int n_in,
                              void* d_out, int out_size, void* d_ws, size_t ws_size,
                              hipStream_t stream)
{
    const float* a0 = (const float*)d_in[0];
    const float* a1 = (const float*)d_in[1];
    const float* a2 = (const float*)d_in[2];
    const float* a3 = (const float*)d_in[3];
    const float* a4 = (const float*)d_in[4];
    const float* bboxs = (const float*)d_in[5];
    const int* hp = (const int*)d_in[6];
    const int* wp = (const int*)d_in[7];

    unsigned* maskbits = (unsigned*)d_ws;
    float* acc = (float*)((char*)d_ws + MASK_BYTES);

    hipMemsetAsync(d_ws, 0, MASK_BYTES + ACC_BYTES, stream);
    raster_kernel<<<B_SZ * 5 * N_BOX, 64, 0, stream>>>(bboxs, hp, wp, maskbits);
    bce_kernel<<<1376, 256, 0, stream>>>(a0, a1, a2, a3, a4, maskbits, acc);
    finalize_kernel<<<1, 256, 0, stream>>>(bboxs, hp, wp, acc, (float*)d_out);
}

// Round 3
// 41.467 us; speedup vs baseline: 3.6179x; 1.0022x over previous
//
#include <hip/hip_runtime.h>

#define B_SZ 16
#define N_BOX 96
#define EPSF 1e-7f

// ---- static geometry -------------------------------------------------------
// level l: hl = wl = 1024 >> l, plane_px = wl*wl
// plane px: 1048576, 262144, 65536, 16384, 4096
// bit offsets (bits) = 16 * cumulative plane sizes
// total bits = 22347776 -> 698368 words -> 2793472 bytes
#define MASK_BYTES 2793472u
#define ACC_STRIDE 32            // floats; 128 B per (b,l) slot -> own cacheline
#define ACC_BYTES  (B_SZ * 5 * ACC_STRIDE * 4)
#define CLEAR_F4   ((MASK_BYTES + ACC_BYTES) / 16u)   // 175232 uint4s

__device__ __forceinline__ unsigned level_bit_off(int l) {
    switch (l) {
        case 0:  return 0u;
        case 1:  return 16777216u;
        case 2:  return 20971520u;
        case 3:  return 22020096u;
        default: return 22282240u;
    }
}

// ---- kernel 0: clear workspace (own clear; rocclr fill ran at 71 GB/s) -----
__global__ __launch_bounds__(256)
void clear_kernel(uint4* __restrict__ ws)
{
    unsigned i = blockIdx.x * 256u + threadIdx.x;
    if (i < CLEAR_F4) ws[i] = make_uint4(0u, 0u, 0u, 0u);
}

// ---- kernel 1: rasterize selected boxes into the bit mask ------------------
__global__ __launch_bounds__(64)
void raster_kernel(const float* __restrict__ bboxs,
                   const int* __restrict__ hp, const int* __restrict__ wp,
                   unsigned* __restrict__ maskbits)
{
    int gid = blockIdx.x;                 // [0, B*5*N)
    int n = gid % N_BOX;
    int l = (gid / N_BOX) % 5;
    int b = gid / (N_BOX * 5);

    const float* bx = bboxs + (b * N_BOX + n) * 5;
    float x1 = bx[0], y1 = bx[1], x2 = bx[2], y2 = bx[3], lb = bx[4];
    float Wf = (float)(*wp), Hf = (float)(*hp);

    bool valid = (lb != -1.0f) && (x1 <= Wf) && (y1 <= Hf) && (x2 <= Wf) && (y2 <= Hf);
    if (!valid) return;

    float area = (x2 - x1) * (y2 - y1);
    double based = (double)(32 << l);
    float mn  = (float)(based * based * 0.5);
    float mxv = (float)((based * 1.58) * (based * 1.58) * 2.0);
    if (!(area >= mn && area <= mxv)) return;

    int wl = 1024 >> l;                   // hl == wl
    float sx = (float)wl / Wf;
    float sy = (float)wl / Hf;

    int ix1 = (int)fmaxf(floorf(x1 * sx), 0.0f);
    int iy1 = (int)fmaxf(floorf(y1 * sy), 0.0f);
    int ix2 = (int)fminf(ceilf(x2 * sx) + 1.0f, (float)wl);
    int iy2 = (int)fminf(ceilf(y2 * sy) + 1.0f, (float)wl);
    if (ix2 <= ix1 || iy2 <= iy1) return;

    unsigned bitOff = level_bit_off(l) + (unsigned)b * (unsigned)(wl * wl);
    int nrows = iy2 - iy1;
    for (int rr = (int)threadIdx.x; rr < nrows; rr += 64) {
        int r = iy1 + rr;
        unsigned rs = bitOff + (unsigned)r * (unsigned)wl + (unsigned)ix1;
        unsigned re = rs + (unsigned)(ix2 - ix1);          // exclusive
        unsigned w0 = rs >> 5, w1 = (re - 1u) >> 5;
        for (unsigned w = w0; w <= w1; ++w) {
            unsigned lo = (w == w0) ? (rs & 31u) : 0u;
            unsigned hi = (w == w1) ? (((re - 1u) & 31u) + 1u) : 32u;
            unsigned m = (hi == 32u ? 0xffffffffu : ((1u << hi) - 1u)) & ~((1u << lo) - 1u);
            atomicOr(&maskbits[w], m);
        }
    }
}

// ---- kernel 2: streaming BCE reduction --------------------------------------
// 2048 f4 per block (l0..l3), 1024 f4 at l4. Blocks per plane:
//   l0:128 l1:32 l2:8 l3:2 l4:1 ; level block starts:
//   l0: 0..2047, l1: 2048..2559, l2: 2560..2687, l3: 2688..2719, l4: 2720..2735
__global__ __launch_bounds__(256)
void bce_kernel(const float* __restrict__ a0, const float* __restrict__ a1,
                const float* __restrict__ a2, const float* __restrict__ a3,
                const float* __restrict__ a4,
                const unsigned* __restrict__ maskbits,
                float* __restrict__ acc)
{
    int bid = blockIdx.x;
    int l, start, bppShift;               // blocksPerPlane = 1<<bppShift
    const float* att;
    if (bid < 2048)      { l = 0; start = 0;    bppShift = 7; att = a0; }
    else if (bid < 2560) { l = 1; start = 2048; bppShift = 5; att = a1; }
    else if (bid < 2688) { l = 2; start = 2560; bppShift = 3; att = a2; }
    else if (bid < 2720) { l = 3; start = 2688; bppShift = 1; att = a3; }
    else                 { l = 4; start = 2720; bppShift = 0; att = a4; }

    int planeF4 = 1 << (18 - 2 * l);      // plane_px / 4
    int bil = bid - start;
    int b     = bil >> bppShift;
    int chunk = bil & ((1 << bppShift) - 1);
    int nf4   = planeF4 >> bppShift;      // 2048, or 1024 at l4
    unsigned gf4base = (unsigned)b * (unsigned)planeF4
                     + (unsigned)chunk * (unsigned)nf4 + threadIdx.x;
    unsigned lvlBit  = level_bit_off(l);

    float s = 0.0f;
    if (nf4 == 2048) {
        float4 av[8];
        unsigned nib[8];
        #pragma unroll
        for (int u = 0; u < 8; ++u) {
            unsigned gf4 = gf4base + (unsigned)(u * 256);
            av[u] = reinterpret_cast<const float4*>(att)[gf4];
            unsigned bidx = lvlBit + gf4 * 4u;
            nib[u] = (maskbits[bidx >> 5] >> (bidx & 31u)) & 0xFu;
        }
        #pragma unroll
        for (int u = 0; u < 8; ++u) {
            float pv[4] = {av[u].x, av[u].y, av[u].z, av[u].w};
            #pragma unroll
            for (int j = 0; j < 4; ++j) {
                float p = fminf(fmaxf(pv[j], EPSF), 1.0f - EPSF);
                float q = ((nib[u] >> j) & 1u) ? p : (1.0f - p);
                s -= __logf(q);
            }
        }
    } else {                              // l4: 4 f4 per thread
        float4 av[4];
        unsigned nib[4];
        #pragma unroll
        for (int u = 0; u < 4; ++u) {
            unsigned gf4 = gf4base + (unsigned)(u * 256);
            av[u] = reinterpret_cast<const float4*>(att)[gf4];
            unsigned bidx = lvlBit + gf4 * 4u;
            nib[u] = (maskbits[bidx >> 5] >> (bidx & 31u)) & 0xFu;
        }
        #pragma unroll
        for (int u = 0; u < 4; ++u) {
            float pv[4] = {av[u].x, av[u].y, av[u].z, av[u].w};
            #pragma unroll
            for (int j = 0; j < 4; ++j) {
                float p = fminf(fmaxf(pv[j], EPSF), 1.0f - EPSF);
                float q = ((nib[u] >> j) & 1u) ? p : (1.0f - p);
                s -= __logf(q);
            }
        }
    }

    // wave reduce (64-wide) then LDS across 4 waves
    #pragma unroll
    for (int off = 32; off > 0; off >>= 1)
        s += __shfl_down(s, off, 64);
    __shared__ float wsum[4];
    int lane = threadIdx.x & 63, wv = threadIdx.x >> 6;
    if (lane == 0) wsum[wv] = s;
    __syncthreads();
    if (threadIdx.x == 0) {
        float t = wsum[0] + wsum[1] + wsum[2] + wsum[3];
        atomicAdd(&acc[(b * 5 + l) * ACC_STRIDE], t);
    }
}

// ---- kernel 3: finalize ------------------------------------------------------
__global__ __launch_bounds__(256)
void finalize_kernel(const float* __restrict__ bboxs,
                     const int* __restrict__ hp, const int* __restrict__ wp,
                     const float* __restrict__ acc, float* __restrict__ out)
{
    __shared__ int hasbox[B_SZ];
    if (threadIdx.x < B_SZ) hasbox[threadIdx.x] = 0;
    __syncthreads();
    float Wf = (float)(*wp), Hf = (float)(*hp);
    for (int i = (int)threadIdx.x; i < B_SZ * N_BOX; i += 256) {
        const float* bx = bboxs + i * 5;
        if (bx[4] != -1.0f && bx[0] <= Wf && bx[1] <= Hf && bx[2] <= Wf && bx[3] <= Hf)
            hasbox[i / N_BOX] = 1;        // benign race, same value
    }
    __syncthreads();
    if (threadIdx.x == 0) {
        double tot = 0.0;
        for (int b = 0; b < B_SZ; ++b) {
            if (!hasbox[b]) continue;
            double s = 0.0;
            for (int l = 0; l < 5; ++l) {
                int wl = 1024 >> l;
                s += (double)acc[(b * 5 + l) * ACC_STRIDE] / (double)(wl * wl);
            }
            tot += s / 5.0;
        }
        out[0] = (float)(tot / (double)B_SZ);
    }
}

// ---- launch ------------------------------------------------------------------
extern "C" void kernel_launch(void* const* d_in, const int* in_sizes, int n_in,
                              void* d_out, int out_size, void* d_ws, size_t ws_size,
                              hipStream_t stream)
{
    const float* a0 = (const float*)d_in[0];
    const float* a1 = (const float*)d_in[1];
    const float* a2 = (const float*)d_in[2];
    const float* a3 = (const float*)d_in[3];
    const float* a4 = (const float*)d_in[4];
    const float* bboxs = (const float*)d_in[5];
    const int* hp = (const int*)d_in[6];
    const int* wp = (const int*)d_in[7];

    unsigned* maskbits = (unsigned*)d_ws;
    float* acc = (float*)((char*)d_ws + MASK_BYTES);

    clear_kernel<<<(CLEAR_F4 + 255u) / 256u, 256, 0, stream>>>((uint4*)d_ws);
    raster_kernel<<<B_SZ * 5 * N_BOX, 64, 0, stream>>>(bboxs, hp, wp, maskbits);
    bce_kernel<<<2736, 256, 0, stream>>>(a0, a1, a2, a3, a4, maskbits, acc);
    finalize_kernel<<<1, 256, 0, stream>>>(bboxs, hp, wp, acc, (float*)d_out);
}